// Round 4
// baseline (89.718 us; speedup 1.0000x reference)
//
#include <hip/hip_runtime.h>

#define NS 1024      // N samples
#define MM 64        // M patches
#define CC 4         // C compartments
#define NSTEPS 100
#define CLIPMAX 1e10f

// One wave (64 threads) per sample. All state in registers:
//   Rrow[k] = R[n, lane, k]                      (phase B matvec, lane = j)
//   Gcol[j] = beta * Rt[n, lane, j] / ntot[j]    (phase A product, lane = i)
// p[k] is broadcast via LDS (write 1 dword, read back as 16x b128 broadcast
// reads) instead of 64x v_readlane -> kills the VALU->SGPR hazard chain.
// amdgpu_waves_per_eu(1,1) lifts the occupancy-heuristic VGPR cap (r3: the
// allocator held 80 VGPRs and shuffled state through AGPRs).
extern "C" __global__
__attribute__((amdgpu_flat_work_group_size(64, 64), amdgpu_waves_per_eu(1, 1)))
void metapop_kernel(
    const float* __restrict__ R,     // (NS, MM, MM)
    const float* __restrict__ T,     // (NS, CC, CC)
    const float* __restrict__ rho0,  // (NS, MM, CC)
    const float* __restrict__ beta,  // (NS,)
    float* __restrict__ out)         // (NSTEPS, NS, MM, CC)
{
    const int n    = blockIdx.x;
    const int lane = threadIdx.x;    // 0..63

    __shared__ float pbuf[MM];

    const float* Rn = R + (size_t)n * (MM * MM);

    // ---- Rrow: contiguous float4 loads ----
    float Rrow[MM];
    {
        const float4* p4 = (const float4*)(Rn + lane * MM);
        #pragma unroll
        for (int k4 = 0; k4 < MM / 4; ++k4) {
            float4 v = p4[k4];
            Rrow[4*k4+0] = v.x; Rrow[4*k4+1] = v.y;
            Rrow[4*k4+2] = v.z; Rrow[4*k4+3] = v.w;
        }
    }

    // ---- ntot[lane] = sum_i R[n, i, lane]  (column sum; L1-hot after Rrow) ----
    float nt = 0.f;
    #pragma unroll
    for (int i = 0; i < MM; ++i) nt += Rn[i * MM + lane];
    const float binv = beta[n] / nt;     // lane j holds beta/ntot[j]

    // broadcast binv[j] to all lanes through LDS as well (one-time)
    pbuf[lane] = binv;
    __syncthreads();
    float bint[MM];
    {
        const float4* pb4 = (const float4*)pbuf;
        #pragma unroll
        for (int k4 = 0; k4 < MM / 4; ++k4) {
            float4 v = pb4[k4];
            bint[4*k4+0] = v.x; bint[4*k4+1] = v.y;
            bint[4*k4+2] = v.z; bint[4*k4+3] = v.w;
        }
    }
    __syncthreads();

    // ---- Gcol[j] = Rt[n, lane, j] * (beta/ntot[j]) via the transpose bijection ----
    // Rt[n,i,j] = R[(i&15)*64+j, (n&15)*4+(i>>4), n>>4]
    float Gcol[MM];
    {
        const int r4    = (n & 15) << 2;
        const int q     = n >> 4;
        const int sbase = (lane & 15) << 6;
        const int a     = r4 + (lane >> 4);
        #pragma unroll
        for (int j = 0; j < MM; ++j) {
            float v = R[(size_t)(sbase + j) * (MM * MM) + a * MM + q];
            Gcol[j] = v * bint[j];
        }
    }

    // ---- PIN the 128 state registers: opaque to the optimizer, zero cost ----
    #pragma unroll
    for (int k = 0; k < MM; ++k) asm volatile("" : "+v"(Rrow[k]));
    #pragma unroll
    for (int j = 0; j < MM; ++j) asm volatile("" : "+v"(Gcol[j]));

    // ---- T[n] (uniform across lanes -> scalar regs) ----
    float tt[CC][CC];
    {
        const float* Tn = T + n * (CC * CC);
        #pragma unroll
        for (int k = 0; k < CC; ++k)
            #pragma unroll
            for (int l = 0; l < CC; ++l)
                tt[k][l] = Tn[k * CC + l];
    }

    // ---- rho0 ----
    float rh[CC];
    {
        float4 v = *(const float4*)(rho0 + (size_t)n * (MM * CC) + lane * CC);
        rh[0] = v.x; rh[1] = v.y; rh[2] = v.z; rh[3] = v.w;
    }

    float* ob = out + (size_t)n * (MM * CC) + lane * CC;
    const size_t stride = (size_t)NS * MM * CC;

    for (int step = 0; step < NSTEPS; ++step) {
        // trajectory records PRE-update state; fully coalesced float4
        *(float4*)(ob + (size_t)step * stride) =
            make_float4(rh[0], rh[1], rh[2], rh[3]);

        // phase A (lane = i): p = 1 - prod_j (1 - rho1 * Gcol[j]); 4 chains
        const float r1 = rh[1];
        float pr0 = 1.f, pr1 = 1.f, pr2 = 1.f, pr3 = 1.f;
        #pragma unroll
        for (int j = 0; j < 16; ++j) {
            pr0 *= 1.f - r1 * Gcol[j];
            pr1 *= 1.f - r1 * Gcol[j + 16];
            pr2 *= 1.f - r1 * Gcol[j + 32];
            pr3 *= 1.f - r1 * Gcol[j + 48];
        }
        const float p = 1.f - (pr0 * pr1) * (pr2 * pr3);

        // broadcast p across lanes via LDS (single-wave block: cheap barrier)
        pbuf[lane] = p;
        __syncthreads();

        // phase B (lane = j): s = sum_k Rrow[k] * p[k]; 16x b128 broadcast reads
        float s0 = 0.f, s1 = 0.f, s2 = 0.f, s3 = 0.f;
        {
            const float4* pb4 = (const float4*)pbuf;
            #pragma unroll
            for (int k4 = 0; k4 < MM / 4; ++k4) {
                float4 pv = pb4[k4];
                s0 += Rrow[4*k4+0] * pv.x;
                s1 += Rrow[4*k4+1] * pv.y;
                s2 += Rrow[4*k4+2] * pv.z;
                s3 += Rrow[4*k4+3] * pv.w;
            }
        }
        const float ssum = (s0 + s1) + (s2 + s3);
        const float sr   = (rh[0] + rh[1]) + (rh[2] + rh[3]);
        const float ninf = (1.f - sr) * ssum;

        // phase C (all lane-local): rho_new[l] = sum_k rho[k]*T[k,l] (+ninf at l=0)
        float nr[CC];
        #pragma unroll
        for (int l = 0; l < CC; ++l) {
            float v = rh[0] * tt[0][l] + rh[1] * tt[1][l]
                    + rh[2] * tt[2][l] + rh[3] * tt[3][l];
            if (l == 0) v += ninf;
            nr[l] = fminf(fmaxf(v, 0.f), CLIPMAX);
        }
        #pragma unroll
        for (int l = 0; l < CC; ++l) rh[l] = nr[l];
        __syncthreads();   // pbuf reads done before next step's write
    }
}

extern "C" void kernel_launch(void* const* d_in, const int* in_sizes, int n_in,
                              void* d_out, int out_size, void* d_ws, size_t ws_size,
                              hipStream_t stream) {
    const float* R    = (const float*)d_in[0];
    const float* T    = (const float*)d_in[1];
    const float* rho0 = (const float*)d_in[2];
    const float* beta = (const float*)d_in[3];
    float* out = (float*)d_out;
    hipLaunchKernelGGL(metapop_kernel, dim3(NS), dim3(64), 0, stream,
                       R, T, rho0, beta, out);
}